// Round 4
// baseline (268.239 us; speedup 1.0000x reference)
//
#include <hip/hip_runtime.h>
#include <hip/hip_cooperative_groups.h>

namespace cg = cooperative_groups;

// FAVOR+ causal linear attention, fp32 I/O, bf16 MFMA chunked-GEMM, single
// cooperative kernel. B=2, L=4096, H=8, D=64, M=128, chunks C=64 x T=64.
// Block g owns chunks 2g, 2g+1 (cid = bh*64+c):
//   A: stage Vt, features Qf/Kf (MFMA), Kf->LDS, Qf frags->regs,
//      chunk sums KVt(bf16)->ws, ks->ws
//   B: grid-wide exclusive bf16 prefix over chunks (fp32 accum)
//   C: num = Qf*KVpre + mask(Qf Kf^T)*V ; den = Qf*kspre + rowsum ; out
// Only cs (17 MB) round-trips through HBM.

#define B_ 2
#define L_ 4096
#define H_ 8
#define D_ 64
#define M_ 128
#define BH_ 16
#define HD_ 512
#define LHD_ (L_*HD_)
#define C_ 64
#define T_ 64
#define RATIO 0.08838834764831845f
#define EPS 1e-3f
#define REC_CS 8320           // shorts per cs record: 64*128 KVt + 128 ks

#define VT_S 72               // Vt/Kft/Sm row stride (shorts)
#define KF_S 136              // Kf / Qf-C-stage row stride (shorts)
#define SCR_SZ 9216           // shorts: max(128*72 Kft, 64*136 QfC)

typedef __attribute__((ext_vector_type(8))) short bf16x8;
typedef __attribute__((ext_vector_type(4))) float f32x4;

__device__ __forceinline__ short f2bf(float f) {
  union { float f; unsigned u; } x; x.f = f;
  unsigned r = (x.u + 0x7fffu + ((x.u >> 16) & 1u)) >> 16;
  return (short)r;
}
__device__ __forceinline__ float bf2f(short s) {
  union { unsigned u; float f; } x; x.u = ((unsigned)(unsigned short)s) << 16;
  return x.f;
}
__device__ __forceinline__ bf16x8 load_cvt8(const float* p) {
  float4 a = *(const float4*)p;
  float4 b = *(const float4*)(p + 4);
  union { bf16x8 v; short s[8]; } u;
  u.s[0]=f2bf(a.x); u.s[1]=f2bf(a.y); u.s[2]=f2bf(a.z); u.s[3]=f2bf(a.w);
  u.s[4]=f2bf(b.x); u.s[5]=f2bf(b.y); u.s[6]=f2bf(b.z); u.s[7]=f2bf(b.w);
  return u.v;
}
#define MFMA(a,b,c) __builtin_amdgcn_mfma_f32_16x16x32_bf16((a),(b),(c),0,0,0)

// ---------- helpers (no barriers inside) ----------
__device__ __forceinline__ void stageVt(short* Vt, const float* __restrict__ vv,
                                        size_t gbase, int t0, int tid) {
  for (int fi = tid; fi < 64*16; fi += 256) {
    int t = fi >> 4, d4 = (fi & 15)*4;
    float4 v4 = *(const float4*)(vv + gbase + (size_t)(t0+t)*HD_ + d4);
    Vt[(d4+0)*VT_S + t] = f2bf(v4.x);
    Vt[(d4+1)*VT_S + t] = f2bf(v4.y);
    Vt[(d4+2)*VT_S + t] = f2bf(v4.z);
    Vt[(d4+3)*VT_S + t] = f2bf(v4.w);
  }
}

// features: Qf C-layout -> Scr, Kf row-major -> Kf_lds, Qf A-frags -> qfr (regs),
// raw ka accumulators -> kasave (for later Kft write). Own-wave Scr readback only.
__device__ __forceinline__ void features(
    const float* __restrict__ qq, const float* __restrict__ kk,
    const float* __restrict__ P, short* __restrict__ Kf_lds,
    short* __restrict__ Scr, int w, int quad, int l15,
    size_t gbase, int t0, bf16x8 qfr[4], f32x4 kasave[8])
{
  const float* qrow = qq + gbase + (size_t)(t0 + 16*w + l15)*HD_;
  const float* krow = kk + gbase + (size_t)(t0 + 16*w + l15)*HD_;
  bf16x8 aq0 = load_cvt8(qrow + quad*8);
  bf16x8 aq1 = load_cvt8(qrow + 32 + quad*8);
  bf16x8 ak0 = load_cvt8(krow + quad*8);
  bf16x8 ak1 = load_cvt8(krow + 32 + quad*8);
  #pragma unroll
  for (int ct = 0; ct < 8; ++ct) {
    const float* prow = P + (ct*16 + l15)*64;
    bf16x8 bp0 = load_cvt8(prow + quad*8);
    bf16x8 bp1 = load_cvt8(prow + 32 + quad*8);
    f32x4 qa = {0.f,0.f,0.f,0.f}, ka = {0.f,0.f,0.f,0.f};
    qa = MFMA(aq0,bp0,qa); qa = MFMA(aq1,bp1,qa);
    ka = MFMA(ak0,bp0,ka); ka = MFMA(ak1,bp1,ka);
    kasave[ct] = ka;
    #pragma unroll
    for (int reg = 0; reg < 4; ++reg) {
      int trow = 16*w + 4*quad + reg;
      int m = 16*ct + l15;
      Scr   [trow*KF_S + m] = f2bf(fmaxf(qa[reg]*RATIO, 0.f) + EPS);
      Kf_lds[trow*KF_S + m] = f2bf(fmaxf(ka[reg]*RATIO, 0.f) + EPS);
    }
  }
  #pragma unroll
  for (int k2 = 0; k2 < 4; ++k2)   // own-wave rows: no barrier needed
    qfr[k2] = *(const bf16x8*)&Scr[(16*w + l15)*KF_S + k2*32 + quad*8];
}

__device__ __forceinline__ void writeKft(short* Scr, const f32x4 kasave[8],
                                         int w, int quad, int l15) {
  #pragma unroll
  for (int ct = 0; ct < 8; ++ct)
    #pragma unroll
    for (int reg = 0; reg < 4; ++reg)
      Scr[(16*ct + l15)*VT_S + 16*w + 4*quad + reg] =
          f2bf(fmaxf(kasave[ct][reg]*RATIO, 0.f) + EPS);
}

__device__ __forceinline__ void chunkSums(const short* Scr /*Kft*/, const short* Vt,
    unsigned short* __restrict__ csb, int tid, int w, int quad, int l15)
{
  if (tid < 128) {               // ks[m]
    float s = 0.f;
    #pragma unroll 8
    for (int t = 0; t < 64; ++t) s += bf2f(Scr[tid*VT_S + t]);
    csb[8192 + tid] = (unsigned short)f2bf(s);
  }
  bf16x8 av0 = *(const bf16x8*)&Vt[(16*w + l15)*VT_S + quad*8];
  bf16x8 av1 = *(const bf16x8*)&Vt[(16*w + l15)*VT_S + 32 + quad*8];
  #pragma unroll
  for (int mt = 0; mt < 8; ++mt) {
    f32x4 acc = {0.f,0.f,0.f,0.f};
    bf16x8 b0 = *(const bf16x8*)&Scr[(16*mt + l15)*VT_S + quad*8];
    bf16x8 b1 = *(const bf16x8*)&Scr[(16*mt + l15)*VT_S + 32 + quad*8];
    acc = MFMA(av0, b0, acc);
    acc = MFMA(av1, b1, acc);
    #pragma unroll
    for (int reg = 0; reg < 4; ++reg)
      csb[(16*w + 4*quad + reg)*128 + 16*mt + l15] = (unsigned short)f2bf(acc[reg]);
  }
}

__device__ __forceinline__ void prefixB(unsigned short* __restrict__ ws, int gid) {
  if (gid >= BH_*(REC_CS/2)) return;
  int bh = gid / (REC_CS/2), rem = gid % (REC_CS/2);
  unsigned short* base = ws + (size_t)bh*C_*REC_CS + (size_t)rem*2;
  float r0 = 0.f, r1 = 0.f;
  for (int c = 0; c < C_; c += 4) {
    unsigned u[4];
    #pragma unroll
    for (int j = 0; j < 4; ++j)
      u[j] = *(const unsigned*)(base + (size_t)(c+j)*REC_CS);
    #pragma unroll
    for (int j = 0; j < 4; ++j) {
      unsigned pw = (unsigned)(unsigned short)f2bf(r0)
                  | ((unsigned)(unsigned short)f2bf(r1) << 16);
      *(unsigned*)(base + (size_t)(c+j)*REC_CS) = pw;
      r0 += bf2f((short)(u[j] & 0xffffu));
      r1 += bf2f((short)(u[j] >> 16));
    }
  }
}

__device__ __forceinline__ void phaseCcore(
    const unsigned short* __restrict__ csb, const short* Kf_lds, const short* Vt,
    short* Scr /*Sm*/, const float* ksl, const bf16x8 qfr[4],
    float* __restrict__ out, size_t gbase, int t0, int w, int quad, int l15)
{
  f32x4 nacc[4];
  #pragma unroll
  for (int ct = 0; ct < 4; ++ct) { f32x4 z = {0.f,0.f,0.f,0.f}; nacc[ct] = z; }
  #pragma unroll
  for (int k2 = 0; k2 < 4; ++k2)       // num1 = Qf * KV_prefix (B direct global)
    #pragma unroll
    for (int ct = 0; ct < 4; ++ct) {
      bf16x8 bb = *(const bf16x8*)(csb + (16*ct + l15)*128 + k2*32 + quad*8);
      nacc[ct] = MFMA(qfr[k2], bb, nacc[ct]);
    }

  float dp = 0.f;                      // den1 = Qf . ks_prefix
  #pragma unroll
  for (int k2 = 0; k2 < 4; ++k2)
    #pragma unroll
    for (int j = 0; j < 8; ++j)
      dp += bf2f(qfr[k2][j]) * ksl[k2*32 + quad*8 + j];
  dp += __shfl_xor(dp, 16);
  dp += __shfl_xor(dp, 32);            // den1(row=16w+l15) on all quads

  f32x4 sacc[4];                       // S = mask(Qf Kf^T)
  #pragma unroll
  for (int jt = 0; jt < 4; ++jt) { f32x4 z = {0.f,0.f,0.f,0.f}; sacc[jt] = z; }
  #pragma unroll
  for (int k2 = 0; k2 < 4; ++k2)
    #pragma unroll
    for (int jt = 0; jt < 4; ++jt) {
      bf16x8 bb = *(const bf16x8*)&Kf_lds[(16*jt + l15)*KF_S + k2*32 + quad*8];
      sacc[jt] = MFMA(qfr[k2], bb, sacc[jt]);
    }
  float rs[4] = {0.f,0.f,0.f,0.f};
  #pragma unroll
  for (int jt = 0; jt < 4; ++jt)
    #pragma unroll
    for (int reg = 0; reg < 4; ++reg) {
      int row = 16*w + 4*quad + reg;
      int j = 16*jt + l15;
      float val = (j <= row) ? sacc[jt][reg] : 0.f;
      rs[reg] += val;
      Scr[row*VT_S + j] = f2bf(val);   // Sm, own-wave rows only
    }
  #pragma unroll
  for (int reg = 0; reg < 4; ++reg) {
    rs[reg] += __shfl_xor(rs[reg], 1);
    rs[reg] += __shfl_xor(rs[reg], 2);
    rs[reg] += __shfl_xor(rs[reg], 4);
    rs[reg] += __shfl_xor(rs[reg], 8);
  }
  #pragma unroll
  for (int kx = 0; kx < 2; ++kx) {     // num2 = S*V (own-wave Sm rows)
    bf16x8 a = *(const bf16x8*)&Scr[(16*w + l15)*VT_S + kx*32 + quad*8];
    #pragma unroll
    for (int ct = 0; ct < 4; ++ct) {
      bf16x8 bb = *(const bf16x8*)&Vt[(16*ct + l15)*VT_S + kx*32 + quad*8];
      nacc[ct] = MFMA(a, bb, nacc[ct]);
    }
  }
  #pragma unroll
  for (int reg = 0; reg < 4; ++reg) {
    float den1 = __shfl(dp, 4*quad + reg);
    float inv = 1.f / (den1 + rs[reg]);
    int trow = t0 + 16*w + 4*quad + reg;
    #pragma unroll
    for (int ct = 0; ct < 4; ++ct)
      out[gbase + (size_t)trow*HD_ + 16*ct + l15] = nacc[ct][reg] * inv;
  }
}

// ---------------- cooperative fused kernel ----------------
__global__ __launch_bounds__(256, 2) void fused_coop(
    const float* __restrict__ qq, const float* __restrict__ kk,
    const float* __restrict__ vv, const float* __restrict__ P,
    unsigned short* __restrict__ ws, float* __restrict__ out)
{
  __shared__ alignas(16) short Vt[2][64*VT_S];
  __shared__ alignas(16) short Kf[2][64*KF_S];
  __shared__ alignas(16) short Scr[SCR_SZ];
  __shared__ float ksl[2][128];

  cg::grid_group grid = cg::this_grid();
  const int tid = threadIdx.x, w = tid >> 6, quad = (tid >> 4) & 3, l15 = tid & 15;
  const int cid0 = blockIdx.x * 2;
  bf16x8 qfr[2][4];

  // ---- phase A: both chunks ----
  #pragma unroll
  for (int s = 0; s < 2; ++s) {
    const int cid = cid0 + s, bh = cid >> 6, c = cid & 63;
    const size_t gbase = (size_t)(bh >> 3)*LHD_ + (size_t)(bh & 7)*D_;
    const int t0 = c*T_;
    unsigned short* csb = ws + (size_t)cid*REC_CS;

    stageVt(Vt[s], vv, gbase, t0, tid);
    f32x4 kasave[8];
    features(qq, kk, P, Kf[s], Scr, w, quad, l15, gbase, t0, qfr[s], kasave);
    __syncthreads();                 // all qfr extracted; Vt staged
    writeKft(Scr, kasave, w, quad, l15);
    __syncthreads();                 // Kft complete
    chunkSums(Scr, Vt[s], csb, tid, w, quad, l15);
    __syncthreads();                 // Scr reads done before next-chunk reuse
  }

  grid.sync();
  prefixB(ws, blockIdx.x*256 + tid); // exclusive bf16 prefix over chunks
  grid.sync();

  // ---- phase C: both chunks ----
  {
    int s2 = tid >> 7, m = tid & 127;
    const unsigned short* csbS = ws + (size_t)(cid0 + s2)*REC_CS;
    ksl[s2][m] = bf2f((short)csbS[8192 + m]);
  }
  __syncthreads();
  #pragma unroll
  for (int s = 0; s < 2; ++s) {
    const int cid = cid0 + s, bh = cid >> 6, c = cid & 63;
    const size_t gbase = (size_t)(bh >> 3)*LHD_ + (size_t)(bh & 7)*D_;
    const int t0 = c*T_;
    const unsigned short* csb = ws + (size_t)cid*REC_CS;
    phaseCcore(csb, Kf[s], Vt[s], Scr, ksl[s], qfr[s], out, gbase, t0, w, quad, l15);
  }
}

// ---------------- fallback (non-cooperative 3-kernel split) ----------------
__global__ __launch_bounds__(256, 2) void pA(
    const float* __restrict__ qq, const float* __restrict__ kk,
    const float* __restrict__ vv, const float* __restrict__ P,
    unsigned short* __restrict__ ws)
{
  __shared__ alignas(16) short Vt[64*VT_S];
  __shared__ alignas(16) short Kf1[64*KF_S];
  __shared__ alignas(16) short Scr[SCR_SZ];
  const int tid = threadIdx.x, w = tid >> 6, quad = (tid >> 4) & 3, l15 = tid & 15;
  const int cid = blockIdx.x, bh = cid >> 6, c = cid & 63;
  const size_t gbase = (size_t)(bh >> 3)*LHD_ + (size_t)(bh & 7)*D_;
  const int t0 = c*T_;
  unsigned short* csb = ws + (size_t)cid*REC_CS;
  stageVt(Vt, vv, gbase, t0, tid);
  bf16x8 qfr[4]; f32x4 kasave[8];
  features(qq, kk, P, Kf1, Scr, w, quad, l15, gbase, t0, qfr, kasave);
  __syncthreads();
  writeKft(Scr, kasave, w, quad, l15);
  __syncthreads();
  chunkSums(Scr, Vt, csb, tid, w, quad, l15);
}

__global__ __launch_bounds__(256) void pB(unsigned short* __restrict__ ws) {
  prefixB(ws, blockIdx.x*256 + threadIdx.x);
}

__global__ __launch_bounds__(256, 2) void pC(
    const float* __restrict__ qq, const float* __restrict__ kk,
    const float* __restrict__ vv, const float* __restrict__ P,
    unsigned short* __restrict__ ws, float* __restrict__ out)
{
  __shared__ alignas(16) short Vt[64*VT_S];
  __shared__ alignas(16) short Kf1[64*KF_S];
  __shared__ alignas(16) short Scr[SCR_SZ];
  __shared__ float ksl[128];
  const int tid = threadIdx.x, w = tid >> 6, quad = (tid >> 4) & 3, l15 = tid & 15;
  const int cid = blockIdx.x, bh = cid >> 6, c = cid & 63;
  const size_t gbase = (size_t)(bh >> 3)*LHD_ + (size_t)(bh & 7)*D_;
  const int t0 = c*T_;
  const unsigned short* csb = ws + (size_t)cid*REC_CS;
  stageVt(Vt, vv, gbase, t0, tid);
  bf16x8 qfr[4]; f32x4 kasave[8];
  features(qq, kk, P, Kf1, Scr, w, quad, l15, gbase, t0, qfr, kasave);
  if (tid < 128) ksl[tid] = bf2f((short)csb[8192 + tid]);
  __syncthreads();
  phaseCcore(csb, Kf1, Vt, Scr, ksl, qfr, out, gbase, t0, w, quad, l15);
}

extern "C" void kernel_launch(void* const* d_in, const int* in_sizes, int n_in,
                              void* d_out, int out_size, void* d_ws, size_t ws_size,
                              hipStream_t stream) {
  const float* q = (const float*)d_in[0];
  const float* k = (const float*)d_in[1];
  const float* v = (const float*)d_in[2];
  const float* P = (const float*)d_in[3];
  float* out = (float*)d_out;
  unsigned short* ws = (unsigned short*)d_ws;   // uses 17 MB

  void* args[] = {(void*)&q, (void*)&k, (void*)&v, (void*)&P, (void*)&ws, (void*)&out};
  hipError_t e = hipLaunchCooperativeKernel((const void*)fused_coop,
                                            dim3(BH_*C_/2), dim3(256), args, 0, stream);
  if (e != hipSuccess) {               // deterministic fallback: 3-kernel split
    pA<<<dim3(BH_*C_), dim3(256), 0, stream>>>(q, k, v, P, ws);
    pB<<<dim3((BH_*(REC_CS/2) + 255)/256), dim3(256), 0, stream>>>(ws);
    pC<<<dim3(BH_*C_), dim3(256), 0, stream>>>(q, k, v, P, ws, out);
  }
}

// Round 5
// 153.345 us; speedup vs baseline: 1.7493x; 1.7493x over previous
//
#include <hip/hip_runtime.h>

// FAVOR+ causal linear attention, fp32 I/O, bf16 MFMA chunked-GEMM, 3 kernels.
// B=2, L=4096, H=8, D=64, M=128, chunks C=64 x T=64.
//   pA: Kf = relu(ratio*K P^T)+eps (MFMA); chunk sums KVt[d][m] bf16 + ks -> ws
//   pB: exclusive bf16 prefix over chunks per (b,h) (fp32 accumulate)
//   pC: recompute Qf,Kf; num = Qf*KVpre + mask(Qf Kf^T)*V ;
//       den = Qf*kspre + rowsum ; out = num/den
// Only cs (17 MB) round-trips through HBM. No cooperative launch (R4 lesson:
// grid.sync at 2 blocks/CU stalls ~90% of cycles; graph-captured launches are cheap).

#define B_ 2
#define L_ 4096
#define H_ 8
#define D_ 64
#define M_ 128
#define BH_ 16
#define HD_ 512
#define LHD_ (L_*HD_)
#define C_ 64
#define T_ 64
#define RATIO 0.08838834764831845f
#define EPS 1e-3f
#define REC_CS 8320           // shorts per cs record: 64*128 KVt + 128 ks

#define VT_S 72               // Vt/Kft/Sm row stride (shorts)
#define KF_S 136              // Kf row-major / Qf C-stage row stride (shorts)
#define SCR_SZ 9216           // shorts: max(128*72 Kft, 64*136 Qf C-stage)

typedef __attribute__((ext_vector_type(8))) short bf16x8;
typedef __attribute__((ext_vector_type(4))) float f32x4;

__device__ __forceinline__ short f2bf(float f) {
  union { float f; unsigned u; } x; x.f = f;
  unsigned r = (x.u + 0x7fffu + ((x.u >> 16) & 1u)) >> 16;
  return (short)r;
}
__device__ __forceinline__ float bf2f(short s) {
  union { unsigned u; float f; } x; x.u = ((unsigned)(unsigned short)s) << 16;
  return x.f;
}
__device__ __forceinline__ bf16x8 load_cvt8(const float* p) {
  float4 a = *(const float4*)p;
  float4 b = *(const float4*)(p + 4);
  union { bf16x8 v; short s[8]; } u;
  u.s[0]=f2bf(a.x); u.s[1]=f2bf(a.y); u.s[2]=f2bf(a.z); u.s[3]=f2bf(a.w);
  u.s[4]=f2bf(b.x); u.s[5]=f2bf(b.y); u.s[6]=f2bf(b.z); u.s[7]=f2bf(b.w);
  return u.v;
}
#define MFMA(a,b,c) __builtin_amdgcn_mfma_f32_16x16x32_bf16((a),(b),(c),0,0,0)

// ---------- helpers (no barriers inside) ----------
__device__ __forceinline__ void stageVt(short* Vt, const float* __restrict__ vv,
                                        size_t gbase, int t0, int tid) {
  for (int fi = tid; fi < 64*16; fi += 256) {
    int t = fi >> 4, d4 = (fi & 15)*4;
    float4 v4 = *(const float4*)(vv + gbase + (size_t)(t0+t)*HD_ + d4);
    Vt[(d4+0)*VT_S + t] = f2bf(v4.x);
    Vt[(d4+1)*VT_S + t] = f2bf(v4.y);
    Vt[(d4+2)*VT_S + t] = f2bf(v4.z);
    Vt[(d4+3)*VT_S + t] = f2bf(v4.w);
  }
}

__device__ __forceinline__ void chunkSums(const short* Kft, const short* Vt,
    unsigned short* __restrict__ csb, int tid, int w, int quad, int l15)
{
  if (tid < 128) {               // ks[m] = sum_t Kf[t][m]
    float s = 0.f;
    #pragma unroll 8
    for (int t = 0; t < 64; ++t) s += bf2f(Kft[tid*VT_S + t]);
    csb[8192 + tid] = (unsigned short)f2bf(s);
  }
  bf16x8 av0 = *(const bf16x8*)&Vt[(16*w + l15)*VT_S + quad*8];
  bf16x8 av1 = *(const bf16x8*)&Vt[(16*w + l15)*VT_S + 32 + quad*8];
  #pragma unroll
  for (int mt = 0; mt < 8; ++mt) {
    f32x4 acc = {0.f,0.f,0.f,0.f};
    bf16x8 b0 = *(const bf16x8*)&Kft[(16*mt + l15)*VT_S + quad*8];
    bf16x8 b1 = *(const bf16x8*)&Kft[(16*mt + l15)*VT_S + 32 + quad*8];
    acc = MFMA(av0, b0, acc);
    acc = MFMA(av1, b1, acc);
    #pragma unroll
    for (int reg = 0; reg < 4; ++reg)
      csb[(16*w + 4*quad + reg)*128 + 16*mt + l15] = (unsigned short)f2bf(acc[reg]);
  }
}

// ---------------- pA: k-features + chunk sums ----------------
__global__ __launch_bounds__(256, 2) void pA(
    const float* __restrict__ kk, const float* __restrict__ vv,
    const float* __restrict__ P, unsigned short* __restrict__ ws)
{
  __shared__ alignas(16) short Vt[64*VT_S];
  __shared__ alignas(16) short Scr[SCR_SZ];     // Kft [m][t]

  const int tid = threadIdx.x, w = tid >> 6, quad = (tid >> 4) & 3, l15 = tid & 15;
  const int cid = blockIdx.x, bh = cid >> 6, c = cid & 63;
  const size_t gbase = (size_t)(bh >> 3)*LHD_ + (size_t)(bh & 7)*D_;
  const int t0 = c*T_;
  unsigned short* csb = ws + (size_t)cid*REC_CS;

  stageVt(Vt, vv, gbase, t0, tid);

  const float* krow = kk + gbase + (size_t)(t0 + 16*w + l15)*HD_;
  bf16x8 ak0 = load_cvt8(krow + quad*8);
  bf16x8 ak1 = load_cvt8(krow + 32 + quad*8);
  #pragma unroll
  for (int ct = 0; ct < 8; ++ct) {
    const float* prow = P + (ct*16 + l15)*64;
    bf16x8 bp0 = load_cvt8(prow + quad*8);
    bf16x8 bp1 = load_cvt8(prow + 32 + quad*8);
    f32x4 ka = {0.f,0.f,0.f,0.f};
    ka = MFMA(ak0,bp0,ka); ka = MFMA(ak1,bp1,ka);
    #pragma unroll
    for (int reg = 0; reg < 4; ++reg)
      Scr[(16*ct + l15)*VT_S + 16*w + 4*quad + reg] =     // Kft[m][t]
          f2bf(fmaxf(ka[reg]*RATIO, 0.f) + EPS);
  }
  __syncthreads();
  chunkSums(Scr, Vt, csb, tid, w, quad, l15);
}

// ---------------- pB: exclusive bf16 prefix over chunks ----------------
__global__ __launch_bounds__(256) void pB(unsigned short* __restrict__ ws) {
  const int gid = blockIdx.x*256 + threadIdx.x;
  if (gid >= BH_*(REC_CS/2)) return;
  const int bh = gid / (REC_CS/2), rem = gid % (REC_CS/2);
  unsigned short* base = ws + (size_t)bh*C_*REC_CS + (size_t)rem*2;
  float r0 = 0.f, r1 = 0.f;
  for (int c = 0; c < C_; c += 4) {
    unsigned u[4];
    #pragma unroll
    for (int j = 0; j < 4; ++j)
      u[j] = *(const unsigned*)(base + (size_t)(c+j)*REC_CS);
    #pragma unroll
    for (int j = 0; j < 4; ++j) {
      unsigned pw = (unsigned)(unsigned short)f2bf(r0)
                  | ((unsigned)(unsigned short)f2bf(r1) << 16);
      *(unsigned*)(base + (size_t)(c+j)*REC_CS) = pw;
      r0 += bf2f((short)(u[j] & 0xffffu));
      r1 += bf2f((short)(u[j] >> 16));
    }
  }
}

// ---------------- pC: features + num/den + output ----------------
__global__ __launch_bounds__(256, 2) void pC(
    const float* __restrict__ qq, const float* __restrict__ kk,
    const float* __restrict__ vv, const float* __restrict__ P,
    const unsigned short* __restrict__ ws, float* __restrict__ out)
{
  __shared__ alignas(16) short Vt[64*VT_S];
  __shared__ alignas(16) short Kf1[64*KF_S];    // Kf row-major [t][m]
  __shared__ alignas(16) short Scr[SCR_SZ];     // Qf C-stage, then Sm
  __shared__ float ksl[128];

  const int tid = threadIdx.x, w = tid >> 6, quad = (tid >> 4) & 3, l15 = tid & 15;
  const int cid = blockIdx.x, bh = cid >> 6, c = cid & 63;
  const size_t gbase = (size_t)(bh >> 3)*LHD_ + (size_t)(bh & 7)*D_;
  const int t0 = c*T_;
  const unsigned short* csb = ws + (size_t)cid*REC_CS;

  stageVt(Vt, vv, gbase, t0, tid);

  // features: Qf -> Scr (C-layout), Kf -> Kf1 (row-major), Qf A-frags -> regs
  const float* qrow = qq + gbase + (size_t)(t0 + 16*w + l15)*HD_;
  const float* krow = kk + gbase + (size_t)(t0 + 16*w + l15)*HD_;
  bf16x8 aq0 = load_cvt8(qrow + quad*8);
  bf16x8 aq1 = load_cvt8(qrow + 32 + quad*8);
  bf16x8 ak0 = load_cvt8(krow + quad*8);
  bf16x8 ak1 = load_cvt8(krow + 32 + quad*8);
  #pragma unroll
  for (int ct = 0; ct < 8; ++ct) {
    const float* prow = P + (ct*16 + l15)*64;
    bf16x8 bp0 = load_cvt8(prow + quad*8);
    bf16x8 bp1 = load_cvt8(prow + 32 + quad*8);
    f32x4 qa = {0.f,0.f,0.f,0.f}, ka = {0.f,0.f,0.f,0.f};
    qa = MFMA(aq0,bp0,qa); qa = MFMA(aq1,bp1,qa);
    ka = MFMA(ak0,bp0,ka); ka = MFMA(ak1,bp1,ka);
    #pragma unroll
    for (int reg = 0; reg < 4; ++reg) {
      int trow = 16*w + 4*quad + reg;
      int m = 16*ct + l15;
      Scr[trow*KF_S + m] = f2bf(fmaxf(qa[reg]*RATIO, 0.f) + EPS);
      Kf1[trow*KF_S + m] = f2bf(fmaxf(ka[reg]*RATIO, 0.f) + EPS);
    }
  }
  bf16x8 qfr[4];
  #pragma unroll
  for (int k2 = 0; k2 < 4; ++k2)   // own-wave rows: no barrier needed
    qfr[k2] = *(const bf16x8*)&Scr[(16*w + l15)*KF_S + k2*32 + quad*8];
  if (tid < 128) ksl[tid] = bf2f((short)csb[8192 + tid]);
  __syncthreads();                 // Kf1 complete; ksl ready; Scr reusable as Sm

  // num1 = Qf * KV_prefix (B-frags direct from cs, [d][m] bf16)
  f32x4 nacc[4];
  #pragma unroll
  for (int ct = 0; ct < 4; ++ct) { f32x4 z = {0.f,0.f,0.f,0.f}; nacc[ct] = z; }
  #pragma unroll
  for (int k2 = 0; k2 < 4; ++k2)
    #pragma unroll
    for (int ct = 0; ct < 4; ++ct) {
      bf16x8 bb = *(const bf16x8*)(csb + (16*ct + l15)*128 + k2*32 + quad*8);
      nacc[ct] = MFMA(qfr[k2], bb, nacc[ct]);
    }

  // den1 = Qf . ks_prefix
  float dp = 0.f;
  #pragma unroll
  for (int k2 = 0; k2 < 4; ++k2)
    #pragma unroll
    for (int j = 0; j < 8; ++j)
      dp += bf2f(qfr[k2][j]) * ksl[k2*32 + quad*8 + j];
  dp += __shfl_xor(dp, 16);
  dp += __shfl_xor(dp, 32);        // den1(row=16w+l15) on all quads

  // S = mask(Qf Kf^T)
  f32x4 sacc[4];
  #pragma unroll
  for (int jt = 0; jt < 4; ++jt) { f32x4 z = {0.f,0.f,0.f,0.f}; sacc[jt] = z; }
  #pragma unroll
  for (int k2 = 0; k2 < 4; ++k2)
    #pragma unroll
    for (int jt = 0; jt < 4; ++jt) {
      bf16x8 bb = *(const bf16x8*)&Kf1[(16*jt + l15)*KF_S + k2*32 + quad*8];
      sacc[jt] = MFMA(qfr[k2], bb, sacc[jt]);
    }
  float rs[4] = {0.f,0.f,0.f,0.f};
  #pragma unroll
  for (int jt = 0; jt < 4; ++jt)
    #pragma unroll
    for (int reg = 0; reg < 4; ++reg) {
      int row = 16*w + 4*quad + reg;
      int j = 16*jt + l15;
      float val = (j <= row) ? sacc[jt][reg] : 0.f;
      rs[reg] += val;
      Scr[row*VT_S + j] = f2bf(val);   // Sm, own-wave rows only
    }
  #pragma unroll
  for (int reg = 0; reg < 4; ++reg) {
    rs[reg] += __shfl_xor(rs[reg], 1);
    rs[reg] += __shfl_xor(rs[reg], 2);
    rs[reg] += __shfl_xor(rs[reg], 4);
    rs[reg] += __shfl_xor(rs[reg], 8);
  }

  // num2 = S * V (own-wave Sm rows)
  #pragma unroll
  for (int kx = 0; kx < 2; ++kx) {
    bf16x8 a = *(const bf16x8*)&Scr[(16*w + l15)*VT_S + kx*32 + quad*8];
    #pragma unroll
    for (int ct = 0; ct < 4; ++ct) {
      bf16x8 bb = *(const bf16x8*)&Vt[(16*ct + l15)*VT_S + kx*32 + quad*8];
      nacc[ct] = MFMA(a, bb, nacc[ct]);
    }
  }

  // out = num/den
  #pragma unroll
  for (int reg = 0; reg < 4; ++reg) {
    float den1 = __shfl(dp, 4*quad + reg);
    float inv = 1.f / (den1 + rs[reg]);
    int trow = t0 + 16*w + 4*quad + reg;
    #pragma unroll
    for (int ct = 0; ct < 4; ++ct)
      out[gbase + (size_t)trow*HD_ + 16*ct + l15] = nacc[ct][reg] * inv;
  }
}

extern "C" void kernel_launch(void* const* d_in, const int* in_sizes, int n_in,
                              void* d_out, int out_size, void* d_ws, size_t ws_size,
                              hipStream_t stream) {
  const float* q = (const float*)d_in[0];
  const float* k = (const float*)d_in[1];
  const float* v = (const float*)d_in[2];
  const float* P = (const float*)d_in[3];
  float* out = (float*)d_out;
  unsigned short* ws = (unsigned short*)d_ws;   // uses 17 MB

  pA<<<dim3(BH_*C_), dim3(256), 0, stream>>>(k, v, P, ws);
  pB<<<dim3((BH_*(REC_CS/2) + 255)/256), dim3(256), 0, stream>>>(ws);
  pC<<<dim3(BH_*C_), dim3(256), 0, stream>>>(q, k, v, P, ws, out);
}

// Round 7
// 153.163 us; speedup vs baseline: 1.7513x; 1.0012x over previous
//
#include <hip/hip_runtime.h>

// FAVOR+ causal linear attention, fp32 I/O, bf16 MFMA chunked-GEMM, 3 kernels.
// B=2, L=4096, H=8, D=64, M=128, chunks C=64 x T=64.
//  K1: Qf,Kf = relu(ratio*X P^T)+eps -> ws ([t][m] bf16, frag-native);
//      V^T bf16 -> ws; chunk sums KVt[d][m] bf16 + ks -> ws. One barrier.
//  K2: exclusive bf16 prefix over chunks per (b,h), software-pipelined.
//  K3: num = Qf*KVpre + mask(Qf Kf^T)*V ; den = Qf*kspre + rowsum(S);
//      out = num/den. All operands direct-from-global frags; LDS = Sm only;
//      ZERO __syncthreads. R6 bug fixed: V^T ws write now covers all 64
//      shorts/row (was writing 8 of every 16 -> half of V poisoned).

#define B_ 2
#define L_ 4096
#define H_ 8
#define D_ 64
#define M_ 128
#define BH_ 16
#define HD_ 512
#define LHD_ (L_*HD_)
#define C_ 64
#define T_ 64
#define RATIO 0.08838834764831845f
#define EPS 1e-3f

#define REC_CS 8320            // shorts per cs record: 64*128 KVt + 128 ks
#define REC_F  8192            // shorts per qf/kf record: 64*128
#define REC_V  4096            // shorts per vt record: 64*64
#define QF_OFF ((size_t)BH_*C_*REC_CS)
#define KF_OFF (QF_OFF + (size_t)BH_*C_*REC_F)
#define VT_OFF (KF_OFF + (size_t)BH_*C_*REC_F)   // total ~58.7 MB (ws = 268 MB)

#define VT_S 72                // LDS row stride (shorts): 36 words ≡ 4 mod 32 (2-way, free)

typedef __attribute__((ext_vector_type(8))) short bf16x8;
typedef __attribute__((ext_vector_type(4))) float f32x4;

__device__ __forceinline__ short f2bf(float f) {
  union { float f; unsigned u; } x; x.f = f;
  unsigned r = (x.u + 0x7fffu + ((x.u >> 16) & 1u)) >> 16;
  return (short)r;
}
__device__ __forceinline__ float bf2f(short s) {
  union { unsigned u; float f; } x; x.u = ((unsigned)(unsigned short)s) << 16;
  return x.f;
}
__device__ __forceinline__ bf16x8 load_cvt8(const float* p) {
  float4 a = *(const float4*)p;
  float4 b = *(const float4*)(p + 4);
  union { bf16x8 v; short s[8]; } u;
  u.s[0]=f2bf(a.x); u.s[1]=f2bf(a.y); u.s[2]=f2bf(a.z); u.s[3]=f2bf(a.w);
  u.s[4]=f2bf(b.x); u.s[5]=f2bf(b.y); u.s[6]=f2bf(b.z); u.s[7]=f2bf(b.w);
  return u.v;
}
#define MFMA(a,b,c) __builtin_amdgcn_mfma_f32_16x16x32_bf16((a),(b),(c),0,0,0)

// ---------------- K1: features + V^T + chunk sums ----------------
__global__ __launch_bounds__(256, 2) void K1(
    const float* __restrict__ qq, const float* __restrict__ kk,
    const float* __restrict__ vv, const float* __restrict__ P,
    unsigned short* __restrict__ ws)
{
  __shared__ alignas(16) short Vt[64*VT_S];     // [d][t]
  __shared__ alignas(16) short Kft[128*VT_S];   // [m][t]
  __shared__ float ksp[4][128];

  const int tid = threadIdx.x, w = tid >> 6, quad = (tid >> 4) & 3, l15 = tid & 15;
  const int cid = blockIdx.x, bh = cid >> 6, c = cid & 63;
  const size_t gbase = (size_t)(bh >> 3)*LHD_ + (size_t)(bh & 7)*D_;
  const int t0 = c*T_;
  unsigned short* csb = ws + (size_t)cid*REC_CS;
  unsigned short* qfb = ws + QF_OFF + (size_t)cid*REC_F;
  unsigned short* kfb = ws + KF_OFF + (size_t)cid*REC_F;
  unsigned short* vtb = ws + VT_OFF + (size_t)cid*REC_V;

  // stage V^T into LDS
  for (int fi = tid; fi < 64*16; fi += 256) {
    int t = fi >> 4, d4 = (fi & 15)*4;
    float4 v4 = *(const float4*)(vv + gbase + (size_t)(t0+t)*HD_ + d4);
    Vt[(d4+0)*VT_S + t] = f2bf(v4.x);
    Vt[(d4+1)*VT_S + t] = f2bf(v4.y);
    Vt[(d4+2)*VT_S + t] = f2bf(v4.z);
    Vt[(d4+3)*VT_S + t] = f2bf(v4.w);
  }

  // features for rows [16w,16w+16): q and k share P B-frags
  const float* qrow = qq + gbase + (size_t)(t0 + 16*w + l15)*HD_;
  const float* krow = kk + gbase + (size_t)(t0 + 16*w + l15)*HD_;
  bf16x8 aq0 = load_cvt8(qrow + quad*8);
  bf16x8 aq1 = load_cvt8(qrow + 32 + quad*8);
  bf16x8 ak0 = load_cvt8(krow + quad*8);
  bf16x8 ak1 = load_cvt8(krow + 32 + quad*8);
  #pragma unroll
  for (int ct = 0; ct < 8; ++ct) {
    const float* prow = P + (ct*16 + l15)*64;
    bf16x8 bp0 = load_cvt8(prow + quad*8);
    bf16x8 bp1 = load_cvt8(prow + 32 + quad*8);
    f32x4 qa = {0.f,0.f,0.f,0.f}, ka = {0.f,0.f,0.f,0.f};
    qa = MFMA(aq0,bp0,qa); qa = MFMA(aq1,bp1,qa);
    ka = MFMA(ak0,bp0,ka); ka = MFMA(ak1,bp1,ka);
    float s = 0.f;
    #pragma unroll
    for (int reg = 0; reg < 4; ++reg) {
      int trow = 16*w + 4*quad + reg;
      int m = 16*ct + l15;
      float qv = fmaxf(qa[reg]*RATIO, 0.f) + EPS;
      float kv = fmaxf(ka[reg]*RATIO, 0.f) + EPS;
      short ks_ = f2bf(kv);
      qfb[trow*128 + m] = (unsigned short)f2bf(qv);
      kfb[trow*128 + m] = (unsigned short)ks_;
      Kft[m*VT_S + trow] = ks_;
      s += kv;
    }
    s += __shfl_xor(s, 16);
    s += __shfl_xor(s, 32);          // sum over this wave's 16 t rows
    if (quad == 0) ksp[w][16*ct + l15] = s;
  }
  __syncthreads();

  // V^T -> ws (vectorized from LDS; 2 iters x 8 shorts covers all 64*64)
  for (int fi = tid; fi < 64*8; fi += 256) {
    int d = fi >> 3, part = fi & 7;
    *(bf16x8*)(vtb + d*64 + part*8) = *(const bf16x8*)&Vt[d*VT_S + part*8];
  }
  // ks -> ws
  if (tid < 128)
    csb[8192 + tid] = (unsigned short)f2bf(
        ksp[0][tid] + ksp[1][tid] + ksp[2][tid] + ksp[3][tid]);

  // KVt[d][m] = sum_t V^T[d][t] * Kf[t][m]; wave w owns d-tile w
  bf16x8 av0 = *(const bf16x8*)&Vt[(16*w + l15)*VT_S + quad*8];
  bf16x8 av1 = *(const bf16x8*)&Vt[(16*w + l15)*VT_S + 32 + quad*8];
  #pragma unroll
  for (int mt = 0; mt < 8; ++mt) {
    f32x4 acc = {0.f,0.f,0.f,0.f};
    bf16x8 b0 = *(const bf16x8*)&Kft[(16*mt + l15)*VT_S + quad*8];
    bf16x8 b1 = *(const bf16x8*)&Kft[(16*mt + l15)*VT_S + 32 + quad*8];
    acc = MFMA(av0, b0, acc);
    acc = MFMA(av1, b1, acc);
    #pragma unroll
    for (int reg = 0; reg < 4; ++reg)
      csb[(16*w + 4*quad + reg)*128 + 16*mt + l15] = (unsigned short)f2bf(acc[reg]);
  }
}

// ---------------- K2: exclusive bf16 prefix, software-pipelined ----------------
__global__ __launch_bounds__(256) void K2(unsigned short* __restrict__ ws) {
  const int gid = blockIdx.x*256 + threadIdx.x;
  if (gid >= BH_*(REC_CS/2)) return;
  const int bh = gid / (REC_CS/2), rem = gid % (REC_CS/2);
  unsigned short* base = ws + (size_t)bh*C_*REC_CS + (size_t)rem*2;
  float r0 = 0.f, r1 = 0.f;
  unsigned cur[4], nxt[4];
  #pragma unroll
  for (int j = 0; j < 4; ++j)
    cur[j] = *(const unsigned*)(base + (size_t)j*REC_CS);
  for (int b = 0; b < 16; ++b) {
    if (b < 15) {
      #pragma unroll
      for (int j = 0; j < 4; ++j)              // prefetch next batch before stores
        nxt[j] = *(const unsigned*)(base + (size_t)(4*b+4+j)*REC_CS);
    }
    #pragma unroll
    for (int j = 0; j < 4; ++j) {
      unsigned pw = (unsigned)(unsigned short)f2bf(r0)
                  | ((unsigned)(unsigned short)f2bf(r1) << 16);
      *(unsigned*)(base + (size_t)(4*b+j)*REC_CS) = pw;
      r0 += bf2f((short)(cur[j] & 0xffffu));
      r1 += bf2f((short)(cur[j] >> 16));
    }
    if (b < 15) {
      #pragma unroll
      for (int j = 0; j < 4; ++j) cur[j] = nxt[j];
    }
  }
}

// ---------------- K3: output (no barriers, LDS = Sm only) ----------------
__global__ __launch_bounds__(256, 4) void K3(
    const unsigned short* __restrict__ ws, float* __restrict__ out)
{
  __shared__ alignas(16) short Sm[64*VT_S];    // [i][j], own-wave rows only

  const int tid = threadIdx.x, w = tid >> 6, quad = (tid >> 4) & 3, l15 = tid & 15;
  const int cid = blockIdx.x, bh = cid >> 6, c = cid & 63;
  const size_t gbase = (size_t)(bh >> 3)*LHD_ + (size_t)(bh & 7)*D_;
  const int t0 = c*T_;
  const unsigned short* csb = ws + (size_t)cid*REC_CS;
  const unsigned short* qfb = ws + QF_OFF + (size_t)cid*REC_F;
  const unsigned short* kfb = ws + KF_OFF + (size_t)cid*REC_F;
  const unsigned short* vtb = ws + VT_OFF + (size_t)cid*REC_V;

  // Qf A-frags (row 16w+l15) direct from global
  bf16x8 qf[4];
  #pragma unroll
  for (int k2 = 0; k2 < 4; ++k2)
    qf[k2] = *(const bf16x8*)(qfb + (16*w + l15)*128 + k2*32 + quad*8);

  // den1 = Qf . ks_prefix (ks bf16 direct from global, per-lane slice)
  float dp = 0.f;
  #pragma unroll
  for (int k2 = 0; k2 < 4; ++k2) {
    bf16x8 kv8 = *(const bf16x8*)(csb + 8192 + k2*32 + quad*8);
    #pragma unroll
    for (int j = 0; j < 8; ++j)
      dp += bf2f(qf[k2][j]) * bf2f(kv8[j]);
  }
  dp += __shfl_xor(dp, 16);
  dp += __shfl_xor(dp, 32);          // den1(row=16w+l15) on all quads

  // num1 = Qf * KV_prefix (B-frags direct from cs, [d][m])
  f32x4 nacc[4];
  #pragma unroll
  for (int ct = 0; ct < 4; ++ct) { f32x4 z = {0.f,0.f,0.f,0.f}; nacc[ct] = z; }
  #pragma unroll
  for (int k2 = 0; k2 < 4; ++k2)
    #pragma unroll
    for (int ct = 0; ct < 4; ++ct) {
      bf16x8 bb = *(const bf16x8*)(csb + (16*ct + l15)*128 + k2*32 + quad*8);
      nacc[ct] = MFMA(qf[k2], bb, nacc[ct]);
    }

  // S = mask(Qf Kf^T) (B-frags direct from kf, [t][m])
  f32x4 sacc[4];
  #pragma unroll
  for (int jt = 0; jt < 4; ++jt) { f32x4 z = {0.f,0.f,0.f,0.f}; sacc[jt] = z; }
  #pragma unroll
  for (int k2 = 0; k2 < 4; ++k2)
    #pragma unroll
    for (int jt = 0; jt < 4; ++jt) {
      bf16x8 bb = *(const bf16x8*)(kfb + (16*jt + l15)*128 + k2*32 + quad*8);
      sacc[jt] = MFMA(qf[k2], bb, sacc[jt]);
    }
  float rs[4] = {0.f,0.f,0.f,0.f};
  #pragma unroll
  for (int jt = 0; jt < 4; ++jt)
    #pragma unroll
    for (int reg = 0; reg < 4; ++reg) {
      int row = 16*w + 4*quad + reg;
      int j = 16*jt + l15;
      float val = (j <= row) ? sacc[jt][reg] : 0.f;
      rs[reg] += val;
      Sm[row*VT_S + j] = f2bf(val);     // own-wave rows only
    }
  #pragma unroll
  for (int reg = 0; reg < 4; ++reg) {
    rs[reg] += __shfl_xor(rs[reg], 1);
    rs[reg] += __shfl_xor(rs[reg], 2);
    rs[reg] += __shfl_xor(rs[reg], 4);
    rs[reg] += __shfl_xor(rs[reg], 8);
  }

  // num2 = S * V (A = own-wave Sm rows, B = V^T frags direct from global)
  #pragma unroll
  for (int kx = 0; kx < 2; ++kx) {
    bf16x8 a = *(const bf16x8*)&Sm[(16*w + l15)*VT_S + kx*32 + quad*8];
    #pragma unroll
    for (int ct = 0; ct < 4; ++ct) {
      bf16x8 bb = *(const bf16x8*)(vtb + (16*ct + l15)*64 + kx*32 + quad*8);
      nacc[ct] = MFMA(a, bb, nacc[ct]);
    }
  }

  // out = num/den
  #pragma unroll
  for (int reg = 0; reg < 4; ++reg) {
    float den1 = __shfl(dp, 4*quad + reg);
    float inv = 1.f / (den1 + rs[reg]);
    int trow = t0 + 16*w + 4*quad + reg;
    #pragma unroll
    for (int ct = 0; ct < 4; ++ct)
      out[gbase + (size_t)trow*HD_ + 16*ct + l15] = nacc[ct][reg] * inv;
  }
}

extern "C" void kernel_launch(void* const* d_in, const int* in_sizes, int n_in,
                              void* d_out, int out_size, void* d_ws, size_t ws_size,
                              hipStream_t stream) {
  const float* q = (const float*)d_in[0];
  const float* k = (const float*)d_in[1];
  const float* v = (const float*)d_in[2];
  const float* P = (const float*)d_in[3];
  float* out = (float*)d_out;
  unsigned short* ws = (unsigned short*)d_ws;   // ~59 MB used

  K1<<<dim3(BH_*C_), dim3(256), 0, stream>>>(q, k, v, P, ws);
  K2<<<dim3((BH_*(REC_CS/2) + 255)/256), dim3(256), 0, stream>>>(ws);
  K3<<<dim3(BH_*C_), dim3(256), 0, stream>>>(ws, out);
}